// Round 10
// baseline (306.628 us; speedup 1.0000x reference)
//
#include <hip/hip_runtime.h>
#include <hip/hip_bf16.h>
#include <stdint.h>

#define T_SEQ 2048
#define D_MODEL 2048
#define N_HEADS 16
#define HEAD_DIM 128

typedef __hip_bfloat16 bf16_t;
typedef __attribute__((ext_vector_type(8))) short short8;
typedef __attribute__((ext_vector_type(4))) short short4v;
typedef __attribute__((ext_vector_type(4))) float f32x4;

__device__ __forceinline__ unsigned short f2bf(float x) {
  union { float f; unsigned u; } c; c.f = x;
  unsigned u = c.u;
  u += 0x7fffu + ((u >> 16) & 1u);   // RNE
  return (unsigned short)(u >> 16);
}
__device__ __forceinline__ float bf2f(short v) {
  union { unsigned u; float f; } c;
  c.u = ((unsigned)(unsigned short)v) << 16;
  return c.f;
}
__device__ __forceinline__ void async16(const bf16_t* g, bf16_t* l) {
  __builtin_amdgcn_global_load_lds(
      (const __attribute__((address_space(1))) void*)g,
      (__attribute__((address_space(3))) void*)l, 16, 0, 0);
}

// ---------------- f32 -> bf16 conversion ----------------
__global__ __launch_bounds__(256) void cvt_kernel(const float* __restrict__ in,
                                                  unsigned short* __restrict__ out,
                                                  int n4) {
  int i = blockIdx.x * 256 + threadIdx.x;
  if (i >= n4) return;
  float4 v = ((const float4*)in)[i];
  short4v o;
  o[0] = (short)f2bf(v.x); o[1] = (short)f2bf(v.y);
  o[2] = (short)f2bf(v.z); o[3] = (short)f2bf(v.w);
  ((short4v*)out)[i] = o;
}

// ---------------- GEMM C[M,N] = A[M,K] * B[N,K]^T, 128x256 tile ----------------
// Round-5 kernel verbatim (measured: 115 us QKV, 0 bank conflicts, 2 blocks/CU).
template<int F32OUT>
__global__ __launch_bounds__(512, 4) void gemm_tp_kernel(
    const bf16_t* __restrict__ A, const bf16_t* __restrict__ Bm,
    float* __restrict__ Cf, unsigned short* __restrict__ Cb,
    int M, int N, int K, int nbn) {
  __shared__ bf16_t lds[36864];   // 3 x 12288 elems = 72 KB
  const int tid = threadIdx.x;
  const int w = tid >> 6, lane = tid & 63;
  const int wm = w >> 2, wn = w & 3;
  const int l15 = lane & 15, g = lane >> 4;

  const int nwg = gridDim.x;
  const int cpx = nwg >> 3;
  const int wg = (blockIdx.x & 7) * cpx + (blockIdx.x >> 3);
  const int bm0 = (wg / nbn) * 128, bn0 = (wg % nbn) * 256;

  const int sl = tid >> 3;
  const int su = (tid & 7) ^ (sl & 7);
  const int srow = (sl << 1) | (su >> 2);
  const int sc8 = su & 3;
  const bf16_t* agA = A + (size_t)(bm0 + srow) * K + sc8 * 8;
  const bf16_t* agB = Bm + (size_t)(bn0 + srow) * K + sc8 * 8;

#define STAGE(KT, SB) do {                                                    \
    bf16_t* _d = lds + (SB) * 12288 + w * 512;                                \
    async16(agA + (size_t)(KT) * 32, _d);                                     \
    async16(agB + (size_t)(KT) * 32, _d + 4096);                              \
    async16(agB + 128 * (size_t)K + (size_t)(KT) * 32, _d + 8192);            \
  } while (0)

  const int lhalf = l15 >> 1;
  const int aoff = lhalf * 64 + (((((l15 & 1) << 2) | g) ^ lhalf)) * 8;
  const bf16_t* Abase = lds + wm * 2048 + aoff;
  const bf16_t* Bbase = lds + 4096 + wn * 2048 + aoff;

  f32x4 acc[4][4];
#pragma unroll
  for (int i = 0; i < 4; ++i)
#pragma unroll
    for (int j = 0; j < 4; ++j)
#pragma unroll
      for (int e = 0; e < 4; ++e) acc[i][j][e] = 0.0f;

  STAGE(0, 0);
  STAGE(1, 1);

  const int NT = K >> 5;
  int cb = 0, sb = 2;
  for (int kt = 0; kt < NT - 1; ++kt) {
    asm volatile("s_waitcnt vmcnt(3)" ::: "memory");
    __builtin_amdgcn_s_barrier();
    const bf16_t* Ab = Abase + cb * 12288;
    const bf16_t* Bb = Bbase + cb * 12288;
    short8 af[4], bfr[4];
#pragma unroll
    for (int mi = 0; mi < 4; ++mi) af[mi] = *(const short8*)(Ab + mi * 512);
#pragma unroll
    for (int ni = 0; ni < 4; ++ni) bfr[ni] = *(const short8*)(Bb + ni * 512);
    if (kt < NT - 2) STAGE(kt + 2, sb);
    __builtin_amdgcn_s_setprio(1);
#pragma unroll
    for (int mi = 0; mi < 4; ++mi)
#pragma unroll
      for (int ni = 0; ni < 4; ++ni)
        acc[mi][ni] = __builtin_amdgcn_mfma_f32_16x16x32_bf16(
            af[mi], bfr[ni], acc[mi][ni], 0, 0, 0);
    __builtin_amdgcn_s_setprio(0);
    cb = (cb == 2) ? 0 : cb + 1;
    sb = (sb == 2) ? 0 : sb + 1;
  }
  {
    asm volatile("s_waitcnt vmcnt(0)" ::: "memory");
    __builtin_amdgcn_s_barrier();
    const bf16_t* Ab = Abase + cb * 12288;
    const bf16_t* Bb = Bbase + cb * 12288;
    short8 af[4], bfr[4];
#pragma unroll
    for (int mi = 0; mi < 4; ++mi) af[mi] = *(const short8*)(Ab + mi * 512);
#pragma unroll
    for (int ni = 0; ni < 4; ++ni) bfr[ni] = *(const short8*)(Bb + ni * 512);
    __builtin_amdgcn_s_setprio(1);
#pragma unroll
    for (int mi = 0; mi < 4; ++mi)
#pragma unroll
      for (int ni = 0; ni < 4; ++ni)
        acc[mi][ni] = __builtin_amdgcn_mfma_f32_16x16x32_bf16(
            af[mi], bfr[ni], acc[mi][ni], 0, 0, 0);
    __builtin_amdgcn_s_setprio(0);
  }
#undef STAGE

#pragma unroll
  for (int mi = 0; mi < 4; ++mi)
#pragma unroll
    for (int ni = 0; ni < 4; ++ni)
#pragma unroll
      for (int r = 0; r < 4; ++r) {
        int mr = bm0 + wm * 64 + mi * 16 + g * 4 + r;
        int nc = bn0 + wn * 64 + ni * 16 + l15;
        if (F32OUT)
          Cf[(size_t)mr * N + nc] = acc[mi][ni][r];
        else
          Cb[(size_t)mr * N + nc] = f2bf(acc[mi][ni][r]);
      }
}

// ---------------- RoPE + split + V transpose ----------------
__global__ __launch_bounds__(256) void rope_kernel(
    const bf16_t* __restrict__ qkv,
    const float* __restrict__ cosb, const float* __restrict__ sinb,
    bf16_t* __restrict__ qo, bf16_t* __restrict__ ko, bf16_t* __restrict__ vT) {
  const int nTT = T_SEQ / 64;
  const int bx = blockIdx.x;
  const int bh = bx / nTT, tt = bx % nTT;
  const int b = bh / N_HEADS, h = bh % N_HEADS;
  const int tid = threadIdx.x;
  __shared__ bf16_t vlds[64][136];

  const float SC = 0.08838834764831845f;  // 1/sqrt(128)

#pragma unroll
  for (int it = 0; it < 2; ++it) {
    int item = it * 256 + tid;
    int r = item >> 3, cg = item & 7;
    int t = tt * 64 + r;
    int c0 = cg * 8;
    size_t base = ((size_t)b * T_SEQ + t) * (size_t)(3 * D_MODEL) + (size_t)h * HEAD_DIM;

    float cs0[8], sn0[8], cs1[8], sn1[8];
    {
      const float* cp = cosb + (size_t)t * HEAD_DIM + c0;
      const float* sp = sinb + (size_t)t * HEAD_DIM + c0;
      float4 a0 = *(const float4*)(cp), a1 = *(const float4*)(cp + 4);
      float4 b0 = *(const float4*)(cp + 64), b1 = *(const float4*)(cp + 68);
      float4 s0 = *(const float4*)(sp), s1 = *(const float4*)(sp + 4);
      float4 t0 = *(const float4*)(sp + 64), t1 = *(const float4*)(sp + 68);
      cs0[0]=a0.x; cs0[1]=a0.y; cs0[2]=a0.z; cs0[3]=a0.w; cs0[4]=a1.x; cs0[5]=a1.y; cs0[6]=a1.z; cs0[7]=a1.w;
      cs1[0]=b0.x; cs1[1]=b0.y; cs1[2]=b0.z; cs1[3]=b0.w; cs1[4]=b1.x; cs1[5]=b1.y; cs1[6]=b1.z; cs1[7]=b1.w;
      sn0[0]=s0.x; sn0[1]=s0.y; sn0[2]=s0.z; sn0[3]=s0.w; sn0[4]=s1.x; sn0[5]=s1.y; sn0[6]=s1.z; sn0[7]=s1.w;
      sn1[0]=t0.x; sn1[1]=t0.y; sn1[2]=t0.z; sn1[3]=t0.w; sn1[4]=t1.x; sn1[5]=t1.y; sn1[6]=t1.z; sn1[7]=t1.w;
    }

#pragma unroll
    for (int sec = 0; sec < 2; ++sec) {
      size_t sbase = base + (size_t)sec * D_MODEL;
      short8 lo = *(const short8*)(qkv + sbase + c0);
      short8 hi = *(const short8*)(qkv + sbase + 64 + c0);
      short8 olo, ohi;
#pragma unroll
      for (int e = 0; e < 8; ++e) {
        float xl = bf2f(lo[e]), xh = bf2f(hi[e]);
        float rl = xl * cs0[e] - xh * sn0[e];
        float rh = xh * cs1[e] + xl * sn1[e];
        if (sec == 0) { rl *= SC; rh *= SC; }
        olo[e] = (short)f2bf(rl);
        ohi[e] = (short)f2bf(rh);
      }
      bf16_t* dst = (sec == 0 ? qo : ko) + ((size_t)bh * T_SEQ + t) * HEAD_DIM + c0;
      *(short8*)dst = olo;
      *(short8*)(dst + 64) = ohi;
    }

    short8 v0 = *(const short8*)(qkv + base + 2 * D_MODEL + c0);
    short8 v1 = *(const short8*)(qkv + base + 2 * D_MODEL + 64 + c0);
    *(short8*)&vlds[r][c0] = v0;
    *(short8*)&vlds[r][64 + c0] = v1;
  }
  __syncthreads();

  int hd = tid >> 1, hf = tid & 1;
  bf16_t* dst = vT + ((size_t)bh * HEAD_DIM + hd) * T_SEQ + tt * 64 + hf * 32;
#pragma unroll
  for (int jj = 0; jj < 4; ++jj) {
    short8 o;
#pragma unroll
    for (int e = 0; e < 8; ++e)
      o[e] = *(const short*)&vlds[hf * 32 + jj * 8 + e][hd];
    *(short8*)(dst + jj * 8) = o;
  }
}

// ---------------- causal flash attention: 2 q-sets/wave, shared K/V reads ----------
// 128 q-rows/block (4 waves x 2 sets of 16), KVBLK=64, 512 blocks (all
// co-resident at 2 blocks/CU; 57.25 KB LDS). DS-traffic-reduction design:
// K fragments read once per iter feed BOTH sets' QK MFMAs; PV is fused so each
// V fragment read feeds BOTH sets. Single-V protocol with counted vmcnt (r9).
// Complementary qt pairing: block j and j+256 sum to constant work per CU.
__global__ __launch_bounds__(256, 2) void attn_kernel(
    const bf16_t* __restrict__ q, const bf16_t* __restrict__ k,
    const bf16_t* __restrict__ vT, unsigned short* __restrict__ attn) {
  const int bx = blockIdx.x;
  const int bh = bx & 31;                 // bx%8 == bh%8 -> head/XCD locality
  const int qi = (bx >> 5) & 7;
  const int qt = (bx >> 8) ? qi : 15 - qi;  // halves pair long+short per CU
  const int b = bh / N_HEADS, h = bh % N_HEADS;
  const int tid = threadIdx.x;
  const int w = tid >> 6, lane = tid & 63;
  const int l15 = lane & 15, g = lane >> 4;
  const int r7 = l15 & 7;
  const float LOG2E = 1.44269504088896340736f;

  __shared__ bf16_t Ks[2][64 * 128];   // 32 KB double-buffered
  __shared__ bf16_t Vs[128 * 64];      // 16 KB single buffer
  __shared__ bf16_t plds[4][16][72];   // 9 KB per-wave P relayout (set-serial)

  const bf16_t* qb = q + (size_t)bh * T_SEQ * HEAD_DIM;
  const bf16_t* kb = k + (size_t)bh * T_SEQ * HEAD_DIM;
  const bf16_t* vb = vT + (size_t)bh * HEAD_DIM * T_SEQ;

  const int qr0 = qt * 128 + w * 16 + l15;
  short8 qf0[4], qf1[4];
#pragma unroll
  for (int kk = 0; kk < 4; ++kk) {
    qf0[kk] = *(const short8*)(qb + (size_t)qr0 * HEAD_DIM + kk * 32 + g * 8);
    qf1[kk] = *(const short8*)(qb + (size_t)(qr0 + 64) * HEAD_DIM + kk * 32 + g * 8);
  }

  float m0[4], l0[4], m1[4], l1[4];
  f32x4 acc0[8], acc1[8];
#pragma unroll
  for (int r = 0; r < 4; ++r) { m0[r] = -3.0e38f; l0[r] = 0.0f; m1[r] = -3.0e38f; l1[r] = 0.0f; }
#pragma unroll
  for (int fh = 0; fh < 8; ++fh)
#pragma unroll
    for (int e = 0; e < 4; ++e) { acc0[fh][e] = 0.0f; acc1[fh][e] = 0.0f; }

#define STAGE_K(KT, BU) {                                                        \
    _Pragma("unroll")                                                            \
    for (int j = 0; j < 4; ++j) {                                                \
      int s = j * 4 + w;                                                         \
      int row = s * 4 + (lane >> 4);                                             \
      int gc = (lane & 15) ^ (row & 7);                                          \
      async16(kb + (size_t)((KT) * 64 + row) * HEAD_DIM + gc * 8,                \
              &Ks[BU][s * 512]);                                                 \
    }                                                                            \
  }
#define STAGE_V(KT) {                                                            \
    _Pragma("unroll")                                                            \
    for (int j = 0; j < 4; ++j) {                                                \
      int s = j * 4 + w;                                                         \
      int row = s * 8 + (lane >> 3);                                             \
      int gc = (lane & 7) ^ (row & 7);                                           \
      async16(vb + (size_t)row * T_SEQ + (KT) * 64 + gc * 8,                     \
              &Vs[s * 512]);                                                     \
    }                                                                            \
  }

  // softmax for one set: updates MM/LL, rescales ACC, emits P-fragments PF0/PF1
#define SM(SX, MM, LL, ACC, PF0, PF1) do {                                       \
    float rmax[4];                                                               \
    _Pragma("unroll")                                                            \
    for (int r = 0; r < 4; ++r)                                                  \
      rmax[r] = fmaxf(fmaxf(SX[0][r], SX[1][r]), fmaxf(SX[2][r], SX[3][r]));     \
    _Pragma("unroll")                                                            \
    for (int off = 1; off < 16; off <<= 1)                                       \
      _Pragma("unroll")                                                          \
      for (int r = 0; r < 4; ++r)                                                \
        rmax[r] = fmaxf(rmax[r], __shfl_xor(rmax[r], off, 64));                  \
    float fac[4], rsum[4];                                                       \
    _Pragma("unroll")                                                            \
    for (int r = 0; r < 4; ++r) {                                                \
      float mn = fmaxf(MM[r], rmax[r]);                                          \
      fac[r] = exp2f((MM[r] - mn) * LOG2E);                                      \
      MM[r] = mn;                                                                \
      rsum[r] = 0.0f;                                                            \
    }                                                                            \
    _Pragma("unroll")                                                            \
    for (int f = 0; f < 4; ++f)                                                  \
      _Pragma("unroll")                                                          \
      for (int r = 0; r < 4; ++r) {                                              \
        float pv = exp2f((SX[f][r] - MM[r]) * LOG2E);                            \
        SX[f][r] = pv;                                                           \
        rsum[r] += pv;                                                           \
      }                                                                          \
    _Pragma("unroll")                                                            \
    for (int off = 1; off < 16; off <<= 1)                                       \
      _Pragma("unroll")                                                          \
      for (int r = 0; r < 4; ++r)                                                \
        rsum[r] += __shfl_xor(rsum[r], off, 64);                                 \
    _Pragma("unroll")                                                            \
    for (int r = 0; r < 4; ++r) LL[r] = LL[r] * fac[r] + rsum[r];                \
    _Pragma("unroll")                                                            \
    for (int fh = 0; fh < 8; ++fh)                                               \
      _Pragma("unroll")                                                          \
      for (int r = 0; r < 4; ++r) ACC[fh][r] *= fac[r];                          \
    _Pragma("unroll")                                                            \
    for (int f = 0; f < 4; ++f)                                                  \
      _Pragma("unroll")                                                          \
      for (int r = 0; r < 4; ++r)                                                \
        *(unsigned short*)&plds[w][g * 4 + r][f * 16 + l15] = f2bf(SX[f][r]);    \
    PF0 = *(const short8*)&plds[w][l15][g * 8];                                  \
    PF1 = *(const short8*)&plds[w][l15][32 + g * 8];                             \
  } while (0)

  STAGE_K(0, 0);

  const int lastk = 2 * qt;
  for (int kt = 0; kt <= lastk; ++kt) {
    const int kbuf = kt & 1;
    // K(kt) is the only outstanding VMEM; drain, then certify globally.
    asm volatile("s_waitcnt vmcnt(0)" ::: "memory");
    __builtin_amdgcn_s_barrier();    // PV(kt-1) done by all + K(kt) landed

    STAGE_V(kt);
    STAGE_K(kt + 1, kbuf ^ 1);       // kt+1 <= 2qt+1 <= 31, always valid

    // ---- QK^T for both sets, shared K fragment reads ----
    f32x4 S0[4], S1[4];
#pragma unroll
    for (int f = 0; f < 4; ++f)
#pragma unroll
      for (int e = 0; e < 4; ++e) { S0[f][e] = 0.0f; S1[f][e] = 0.0f; }
    __builtin_amdgcn_s_setprio(1);
#pragma unroll
    for (int f = 0; f < 4; ++f) {
      int row = f * 16 + l15;
#pragma unroll
      for (int kk = 0; kk < 4; ++kk) {
        short8 kf = *(const short8*)(&Ks[kbuf][row * 128 + (((kk * 4 + g) ^ r7) << 3)]);
        S0[f] = __builtin_amdgcn_mfma_f32_16x16x32_bf16(qf0[kk], kf, S0[f], 0, 0, 0);
        S1[f] = __builtin_amdgcn_mfma_f32_16x16x32_bf16(qf1[kk], kf, S1[f], 0, 0, 0);
      }
    }
    __builtin_amdgcn_s_setprio(0);

    if (kt == lastk) {   // set0 diagonal
#pragma unroll
      for (int f = 0; f < 4; ++f) {
        int kv = f * 16 + l15;
#pragma unroll
        for (int r = 0; r < 4; ++r) {
          int qq = w * 16 + g * 4 + r;
          if (kv > qq) S0[f][r] = -3.0e38f;
        }
      }
    }

    // ---- softmax both sets (independent chains -> ILP over shfl latency) ----
    short8 pf00, pf01, pf10, pf11;
    SM(S0, m0, l0, acc0, pf00, pf01);
    SM(S1, m1, l1, acc1, pf10, pf11);

    // ---- V(kt) landed (own 8 loads: leave K(kt+1)'s 4 in flight) ----
    asm volatile("s_waitcnt vmcnt(4)" ::: "memory");
    __builtin_amdgcn_s_barrier();

    // ---- fused PV: each V fragment read once, feeds both sets ----
    __builtin_amdgcn_s_setprio(1);
#pragma unroll
    for (int fh = 0; fh < 8; ++fh) {
      int row = fh * 16 + l15;
      short8 vf0 = *(const short8*)(&Vs[row * 64 + ((g ^ r7) << 3)]);
      short8 vf1 = *(const short8*)(&Vs[row * 64 + (((4 + g) ^ r7) << 3)]);
      acc0[fh] = __builtin_amdgcn_mfma_f32_16x16x32_bf16(pf00, vf0, acc0[fh], 0, 0, 0);
      acc0[fh] = __builtin_amdgcn_mfma_f32_16x16x32_bf16(pf01, vf1, acc0[fh], 0, 0, 0);
      acc1[fh] = __builtin_amdgcn_mfma_f32_16x16x32_bf16(pf10, vf0, acc1[fh], 0, 0, 0);
      acc1[fh] = __builtin_amdgcn_mfma_f32_16x16x32_bf16(pf11, vf1, acc1[fh], 0, 0, 0);
    }
    __builtin_amdgcn_s_setprio(0);
  }

  // ---- epilogue tile kt = 2qt+1: set1 only, diagonal ----
  {
    const int kbuf = (lastk + 1) & 1;
    asm volatile("s_waitcnt vmcnt(0)" ::: "memory");   // K(2qt+1) landed
    __builtin_amdgcn_s_barrier();                      // + all PV done
    STAGE_V(lastk + 1);

    f32x4 S1[4];
#pragma unroll
    for (int f = 0; f < 4; ++f)
#pragma unroll
      for (int e = 0; e < 4; ++e) S1[f][e] = 0.0f;
    __builtin_amdgcn_s_setprio(1);
#pragma unroll
    for (int f = 0; f < 4; ++f) {
      int row = f * 16 + l15;
#pragma unroll
      for (int kk = 0; kk < 4; ++kk) {
        short8 kf = *(const short8*)(&Ks[kbuf][row * 128 + (((kk * 4 + g) ^ r7) << 3)]);
        S1[f] = __builtin_amdgcn_mfma_f32_16x16x32_bf16(qf1[kk], kf, S1[f], 0, 0, 0);
      }
    }
    __builtin_amdgcn_s_setprio(0);
#pragma unroll
    for (int f = 0; f < 4; ++f) {
      int kv = f * 16 + l15;
#pragma unroll
      for (int r = 0; r < 4; ++r) {
        int qq = w * 16 + g * 4 + r;
        if (kv > qq) S1[f][r] = -3.0e38f;
      }
    }
    short8 pf10, pf11;
    SM(S1, m1, l1, acc1, pf10, pf11);

    asm volatile("s_waitcnt vmcnt(0)" ::: "memory");   // V(2qt+1) landed
    __builtin_amdgcn_s_barrier();

    __builtin_amdgcn_s_setprio(1);
#pragma unroll
    for (int fh = 0; fh < 8; ++fh) {
      int row = fh * 16 + l15;
      short8 vf0 = *(const short8*)(&Vs[row * 64 + ((g ^ r7) << 3)]);
      short8 vf1 = *(const short8*)(&Vs[row * 64 + (((4 + g) ^ r7) << 3)]);
      acc1[fh] = __builtin_amdgcn_mfma_f32_16x16x32_bf16(pf10, vf0, acc1[fh], 0, 0, 0);
      acc1[fh] = __builtin_amdgcn_mfma_f32_16x16x32_bf16(pf11, vf1, acc1[fh], 0, 0, 0);
    }
    __builtin_amdgcn_s_setprio(0);
  }

#undef STAGE_K
#undef STAGE_V
#undef SM

  // ---- write both sets ----
  float inv0[4], inv1[4];
#pragma unroll
  for (int r = 0; r < 4; ++r) { inv0[r] = 1.0f / l0[r]; inv1[r] = 1.0f / l1[r]; }
#pragma unroll
  for (int fh = 0; fh < 8; ++fh)
#pragma unroll
    for (int r = 0; r < 4; ++r) {
      int tg0 = qt * 128 + w * 16 + g * 4 + r;
      size_t col = (size_t)h * HEAD_DIM + fh * 16 + l15;
      attn[((size_t)b * T_SEQ + tg0) * D_MODEL + col] = f2bf(acc0[fh][r] * inv0[r]);
      attn[((size_t)b * T_SEQ + tg0 + 64) * D_MODEL + col] = f2bf(acc1[fh][r] * inv1[r]);
    }
}

// ---------------- launch ----------------
extern "C" void kernel_launch(void* const* d_in, const int* in_sizes, int n_in,
                              void* d_out, int out_size, void* d_ws, size_t ws_size,
                              hipStream_t stream) {
  const float* x    = (const float*)d_in[0];
  const float* cosb = (const float*)d_in[1];
  const float* sinb = (const float*)d_in[2];
  const float* Wqkv = (const float*)d_in[3];
  const float* Wout = (const float*)d_in[4];
  float* out = (float*)d_out;

  char* ws = (char*)d_ws;
  size_t off = 0;
  bf16_t* xb    = (bf16_t*)(ws + off); off += (size_t)4096 * 2048 * 2;
  bf16_t* wqkvb = (bf16_t*)(ws + off); off += (size_t)6144 * 2048 * 2;
  bf16_t* woutb = (bf16_t*)(ws + off); off += (size_t)2048 * 2048 * 2;
  bf16_t* qkvb  = (bf16_t*)(ws + off); off += (size_t)4096 * 6144 * 2;
  bf16_t* qb    = (bf16_t*)(ws + off); off += (size_t)32 * 2048 * 128 * 2;
  bf16_t* kb    = (bf16_t*)(ws + off); off += (size_t)32 * 2048 * 128 * 2;
  bf16_t* vTb   = (bf16_t*)(ws + off); off += (size_t)32 * 2048 * 128 * 2;
  bf16_t* attnb = xb;  // xb dead after QKV GEMM

  cvt_kernel<<<8192, 256, 0, stream>>>(x, (unsigned short*)xb, 4096 * 2048 / 4);
  cvt_kernel<<<12288, 256, 0, stream>>>(Wqkv, (unsigned short*)wqkvb, 6144 * 2048 / 4);
  cvt_kernel<<<4096, 256, 0, stream>>>(Wout, (unsigned short*)woutb, 2048 * 2048 / 4);

  // QKV: M=4096, N=6144 -> 32x24 = 768 blocks
  gemm_tp_kernel<0><<<768, 512, 0, stream>>>(xb, wqkvb, nullptr, (unsigned short*)qkvb,
                                             4096, 6144, 2048, 24);

  rope_kernel<<<1024, 256, 0, stream>>>(qkvb, cosb, sinb, qb, kb, vTb);

  // 512 blocks: 32 bh x 16 q-tiles of 128 rows; all co-resident at 2/CU
  attn_kernel<<<512, 256, 0, stream>>>(qb, kb, vTb, (unsigned short*)attnb);

  // out-proj: M=4096, N=2048 -> 32x8 = 256 blocks
  gemm_tp_kernel<1><<<256, 512, 0, stream>>>(attnb, woutb, out, nullptr,
                                             4096, 2048, 2048, 8);
}

// Round 12
// 274.340 us; speedup vs baseline: 1.1177x; 1.1177x over previous
//
#include <hip/hip_runtime.h>
#include <hip/hip_bf16.h>
#include <stdint.h>

#define T_SEQ 2048
#define D_MODEL 2048
#define N_HEADS 16
#define HEAD_DIM 128

typedef __hip_bfloat16 bf16_t;
typedef __attribute__((ext_vector_type(8))) short short8;
typedef __attribute__((ext_vector_type(4))) short short4v;
typedef __attribute__((ext_vector_type(4))) float f32x4;
typedef __attribute__((ext_vector_type(16))) float f32x16;

__device__ __forceinline__ unsigned short f2bf(float x) {
  union { float f; unsigned u; } c; c.f = x;
  unsigned u = c.u;
  u += 0x7fffu + ((u >> 16) & 1u);   // RNE
  return (unsigned short)(u >> 16);
}
__device__ __forceinline__ float bf2f(short v) {
  union { unsigned u; float f; } c;
  c.u = ((unsigned)(unsigned short)v) << 16;
  return c.f;
}
__device__ __forceinline__ void async16(const bf16_t* g, bf16_t* l) {
  __builtin_amdgcn_global_load_lds(
      (const __attribute__((address_space(1))) void*)g,
      (__attribute__((address_space(3))) void*)l, 16, 0, 0);
}

// ---------------- f32 -> bf16 conversion ----------------
__global__ __launch_bounds__(256) void cvt_kernel(const float* __restrict__ in,
                                                  unsigned short* __restrict__ out,
                                                  int n4) {
  int i = blockIdx.x * 256 + threadIdx.x;
  if (i >= n4) return;
  float4 v = ((const float4*)in)[i];
  short4v o;
  o[0] = (short)f2bf(v.x); o[1] = (short)f2bf(v.y);
  o[2] = (short)f2bf(v.z); o[3] = (short)f2bf(v.w);
  ((short4v*)out)[i] = o;
}

// ---------------- GEMM C[M,N] = A[M,K] * B[N,K]^T, 128x256 tile ----------------
// Round-5 kernel verbatim (measured: 115 us QKV, 0 bank conflicts, 2 blocks/CU).
template<int F32OUT>
__global__ __launch_bounds__(512, 4) void gemm_tp_kernel(
    const bf16_t* __restrict__ A, const bf16_t* __restrict__ Bm,
    float* __restrict__ Cf, unsigned short* __restrict__ Cb,
    int M, int N, int K, int nbn) {
  __shared__ bf16_t lds[36864];   // 3 x 12288 elems = 72 KB
  const int tid = threadIdx.x;
  const int w = tid >> 6, lane = tid & 63;
  const int wm = w >> 2, wn = w & 3;
  const int l15 = lane & 15, g = lane >> 4;

  const int nwg = gridDim.x;
  const int cpx = nwg >> 3;
  const int wg = (blockIdx.x & 7) * cpx + (blockIdx.x >> 3);
  const int bm0 = (wg / nbn) * 128, bn0 = (wg % nbn) * 256;

  const int sl = tid >> 3;
  const int su = (tid & 7) ^ (sl & 7);
  const int srow = (sl << 1) | (su >> 2);
  const int sc8 = su & 3;
  const bf16_t* agA = A + (size_t)(bm0 + srow) * K + sc8 * 8;
  const bf16_t* agB = Bm + (size_t)(bn0 + srow) * K + sc8 * 8;

#define STAGE(KT, SB) do {                                                    \
    bf16_t* _d = lds + (SB) * 12288 + w * 512;                                \
    async16(agA + (size_t)(KT) * 32, _d);                                     \
    async16(agB + (size_t)(KT) * 32, _d + 4096);                              \
    async16(agB + 128 * (size_t)K + (size_t)(KT) * 32, _d + 8192);            \
  } while (0)

  const int lhalf = l15 >> 1;
  const int aoff = lhalf * 64 + (((((l15 & 1) << 2) | g) ^ lhalf)) * 8;
  const bf16_t* Abase = lds + wm * 2048 + aoff;
  const bf16_t* Bbase = lds + 4096 + wn * 2048 + aoff;

  f32x4 acc[4][4];
#pragma unroll
  for (int i = 0; i < 4; ++i)
#pragma unroll
    for (int j = 0; j < 4; ++j)
#pragma unroll
      for (int e = 0; e < 4; ++e) acc[i][j][e] = 0.0f;

  STAGE(0, 0);
  STAGE(1, 1);

  const int NT = K >> 5;
  int cb = 0, sb = 2;
  for (int kt = 0; kt < NT - 1; ++kt) {
    asm volatile("s_waitcnt vmcnt(3)" ::: "memory");
    __builtin_amdgcn_s_barrier();
    const bf16_t* Ab = Abase + cb * 12288;
    const bf16_t* Bb = Bbase + cb * 12288;
    short8 af[4], bfr[4];
#pragma unroll
    for (int mi = 0; mi < 4; ++mi) af[mi] = *(const short8*)(Ab + mi * 512);
#pragma unroll
    for (int ni = 0; ni < 4; ++ni) bfr[ni] = *(const short8*)(Bb + ni * 512);
    if (kt < NT - 2) STAGE(kt + 2, sb);
    __builtin_amdgcn_s_setprio(1);
#pragma unroll
    for (int mi = 0; mi < 4; ++mi)
#pragma unroll
      for (int ni = 0; ni < 4; ++ni)
        acc[mi][ni] = __builtin_amdgcn_mfma_f32_16x16x32_bf16(
            af[mi], bfr[ni], acc[mi][ni], 0, 0, 0);
    __builtin_amdgcn_s_setprio(0);
    cb = (cb == 2) ? 0 : cb + 1;
    sb = (sb == 2) ? 0 : sb + 1;
  }
  {
    asm volatile("s_waitcnt vmcnt(0)" ::: "memory");
    __builtin_amdgcn_s_barrier();
    const bf16_t* Ab = Abase + cb * 12288;
    const bf16_t* Bb = Bbase + cb * 12288;
    short8 af[4], bfr[4];
#pragma unroll
    for (int mi = 0; mi < 4; ++mi) af[mi] = *(const short8*)(Ab + mi * 512);
#pragma unroll
    for (int ni = 0; ni < 4; ++ni) bfr[ni] = *(const short8*)(Bb + ni * 512);
    __builtin_amdgcn_s_setprio(1);
#pragma unroll
    for (int mi = 0; mi < 4; ++mi)
#pragma unroll
      for (int ni = 0; ni < 4; ++ni)
        acc[mi][ni] = __builtin_amdgcn_mfma_f32_16x16x32_bf16(
            af[mi], bfr[ni], acc[mi][ni], 0, 0, 0);
    __builtin_amdgcn_s_setprio(0);
  }
#undef STAGE

#pragma unroll
  for (int mi = 0; mi < 4; ++mi)
#pragma unroll
    for (int ni = 0; ni < 4; ++ni)
#pragma unroll
      for (int r = 0; r < 4; ++r) {
        int mr = bm0 + wm * 64 + mi * 16 + g * 4 + r;
        int nc = bn0 + wn * 64 + ni * 16 + l15;
        if (F32OUT)
          Cf[(size_t)mr * N + nc] = acc[mi][ni][r];
        else
          Cb[(size_t)mr * N + nc] = f2bf(acc[mi][ni][r]);
      }
}

// ---------------- RoPE + split + V transpose ----------------
__global__ __launch_bounds__(256) void rope_kernel(
    const bf16_t* __restrict__ qkv,
    const float* __restrict__ cosb, const float* __restrict__ sinb,
    bf16_t* __restrict__ qo, bf16_t* __restrict__ ko, bf16_t* __restrict__ vT) {
  const int nTT = T_SEQ / 64;
  const int bx = blockIdx.x;
  const int bh = bx / nTT, tt = bx % nTT;
  const int b = bh / N_HEADS, h = bh % N_HEADS;
  const int tid = threadIdx.x;
  __shared__ bf16_t vlds[64][136];

  const float SC = 0.08838834764831845f;  // 1/sqrt(128)

#pragma unroll
  for (int it = 0; it < 2; ++it) {
    int item = it * 256 + tid;
    int r = item >> 3, cg = item & 7;
    int t = tt * 64 + r;
    int c0 = cg * 8;
    size_t base = ((size_t)b * T_SEQ + t) * (size_t)(3 * D_MODEL) + (size_t)h * HEAD_DIM;

    float cs0[8], sn0[8], cs1[8], sn1[8];
    {
      const float* cp = cosb + (size_t)t * HEAD_DIM + c0;
      const float* sp = sinb + (size_t)t * HEAD_DIM + c0;
      float4 a0 = *(const float4*)(cp), a1 = *(const float4*)(cp + 4);
      float4 b0 = *(const float4*)(cp + 64), b1 = *(const float4*)(cp + 68);
      float4 s0 = *(const float4*)(sp), s1 = *(const float4*)(sp + 4);
      float4 t0 = *(const float4*)(sp + 64), t1 = *(const float4*)(sp + 68);
      cs0[0]=a0.x; cs0[1]=a0.y; cs0[2]=a0.z; cs0[3]=a0.w; cs0[4]=a1.x; cs0[5]=a1.y; cs0[6]=a1.z; cs0[7]=a1.w;
      cs1[0]=b0.x; cs1[1]=b0.y; cs1[2]=b0.z; cs1[3]=b0.w; cs1[4]=b1.x; cs1[5]=b1.y; cs1[6]=b1.z; cs1[7]=b1.w;
      sn0[0]=s0.x; sn0[1]=s0.y; sn0[2]=s0.z; sn0[3]=s0.w; sn0[4]=s1.x; sn0[5]=s1.y; sn0[6]=s1.z; sn0[7]=s1.w;
      sn1[0]=t0.x; sn1[1]=t0.y; sn1[2]=t0.z; sn1[3]=t0.w; sn1[4]=t1.x; sn1[5]=t1.y; sn1[6]=t1.z; sn1[7]=t1.w;
    }

#pragma unroll
    for (int sec = 0; sec < 2; ++sec) {
      size_t sbase = base + (size_t)sec * D_MODEL;
      short8 lo = *(const short8*)(qkv + sbase + c0);
      short8 hi = *(const short8*)(qkv + sbase + 64 + c0);
      short8 olo, ohi;
#pragma unroll
      for (int e = 0; e < 8; ++e) {
        float xl = bf2f(lo[e]), xh = bf2f(hi[e]);
        float rl = xl * cs0[e] - xh * sn0[e];
        float rh = xh * cs1[e] + xl * sn1[e];
        if (sec == 0) { rl *= SC; rh *= SC; }
        olo[e] = (short)f2bf(rl);
        ohi[e] = (short)f2bf(rh);
      }
      bf16_t* dst = (sec == 0 ? qo : ko) + ((size_t)bh * T_SEQ + t) * HEAD_DIM + c0;
      *(short8*)dst = olo;
      *(short8*)(dst + 64) = ohi;
    }

    short8 v0 = *(const short8*)(qkv + base + 2 * D_MODEL + c0);
    short8 v1 = *(const short8*)(qkv + base + 2 * D_MODEL + 64 + c0);
    *(short8*)&vlds[r][c0] = v0;
    *(short8*)&vlds[r][64 + c0] = v1;
  }
  __syncthreads();

  int hd = tid >> 1, hf = tid & 1;
  bf16_t* dst = vT + ((size_t)bh * HEAD_DIM + hd) * T_SEQ + tt * 64 + hf * 32;
#pragma unroll
  for (int jj = 0; jj < 4; ++jj) {
    short8 o;
#pragma unroll
    for (int e = 0; e < 8; ++e)
      o[e] = *(const short*)&vlds[hf * 32 + jj * 8 + e][hd];
    *(short8*)(dst + jj * 8) = o;
  }
}

// ---------------- causal flash attention: swapped-QK^T 32x32, in-reg softmax ----
// 4 waves x 32 q-rows = 128 rows/block, KVBLK=64, 512 blocks (2/CU, 64 KB LDS).
// S^T = mfma_32x32x16(K, Q): lane holds col q=lane&31, kv rows
// (r&3)+8*(r>>2)+4*(lane>>5) [m74-verified C/D map]. Softmax in-register:
// fmax/add trees + ONE lane^32 exchange. P -> B-frag: pack BOTH reg-halves
// with v_cvt_pk_bf16_f32; send (hi ? L : H), keep (hi ? H : L) -- r11's bug
// was sending the kept half. PV: O^T = mfma(V^T, P^T). Epilogue transpose via
// LDS stride 136 (16B-aligned rows; 138 broke b128 alignment).
__global__ __launch_bounds__(256, 2) void attn_kernel(
    const bf16_t* __restrict__ q, const bf16_t* __restrict__ k,
    const bf16_t* __restrict__ vT, unsigned short* __restrict__ attn) {
  const int bx = blockIdx.x;
  const int bh = bx & 31;                  // bx%8 == bh%8 -> head/XCD locality
  const int qi = (bx >> 5) & 7;
  const int qt = (bx >> 8) ? qi : 15 - qi; // complementary pairing per CU
  const int b = bh / N_HEADS, h = bh % N_HEADS;
  const int tid = threadIdx.x;
  const int w = tid >> 6, lane = tid & 63;
  const int l31 = lane & 31, hi = lane >> 5;
  const int swz = l31 & 7;
  const float LOG2E = 1.44269504088896340736f;

  __shared__ bf16_t smem[32768];   // K dbuf 2x8192 | V dbuf 2x8192 (elems)

  const bf16_t* qb = q + (size_t)bh * T_SEQ * HEAD_DIM;
  const bf16_t* kb = k + (size_t)bh * T_SEQ * HEAD_DIM;
  const bf16_t* vb = vT + (size_t)bh * HEAD_DIM * T_SEQ;

  const int qlo = qt * 128 + w * 32;
  const int qhi = qlo + 31;
  const int qrow = qlo + l31;

  // Q as B-fragments: lane holds col q=l31; k-elems hd = 16*ks + 8*hi + i
  short8 qf[8];
#pragma unroll
  for (int ks = 0; ks < 8; ++ks)
    qf[ks] = *(const short8*)(qb + (size_t)qrow * HEAD_DIM + ks * 16 + hi * 8);

  float m = -3.0e38f, l = 0.0f;
  f32x16 O[4];
#pragma unroll
  for (int dt = 0; dt < 4; ++dt)
#pragma unroll
    for (int r = 0; r < 16; ++r) O[dt][r] = 0.0f;

#define STAGE_TILES(KT, BU) {                                                    \
    _Pragma("unroll")                                                            \
    for (int j = 0; j < 4; ++j) {                                                \
      int s = j * 4 + w;                                                         \
      int row = s * 4 + (lane >> 4);                                             \
      int gc = (lane & 15) ^ (row & 7);                                          \
      async16(kb + (size_t)((KT) * 64 + row) * HEAD_DIM + gc * 8,                \
              smem + (BU) * 8192 + s * 512);                                     \
    }                                                                            \
    _Pragma("unroll")                                                            \
    for (int j = 0; j < 4; ++j) {                                                \
      int s = j * 4 + w;                                                         \
      int row = s * 8 + (lane >> 3);                                             \
      int gc = (lane & 7) ^ (row & 7);                                           \
      async16(vb + (size_t)row * T_SEQ + (KT) * 64 + gc * 8,                     \
              smem + 16384 + (BU) * 8192 + s * 512);                             \
    }                                                                            \
  }

  STAGE_TILES(0, 0);
  __syncthreads();
  int buf = 0;

  const int lastk = 2 * qt + 1;
  for (int kt = 0; kt <= lastk; ++kt) {
    if (kt < lastk) STAGE_TILES(kt + 1, buf ^ 1);
    const bf16_t* Ks = smem + buf * 8192;
    const bf16_t* Vs = smem + 16384 + buf * 8192;
    const bool active = (kt * 64 <= qhi);   // trailing tiles fully masked for this wave

    if (active) {
      // ---- S^T = K Q^T (two 32-kv tiles) ----
      f32x16 S[2];
#pragma unroll
      for (int kvt = 0; kvt < 2; ++kvt) {
        const int kvbase = kt * 64 + kvt * 32;
        if (kvbase <= qhi) {
          const int krow = kvt * 32 + l31;
#pragma unroll
          for (int r = 0; r < 16; ++r) S[kvt][r] = 0.0f;
          __builtin_amdgcn_s_setprio(1);
#pragma unroll
          for (int ks = 0; ks < 8; ++ks) {
            int c = (2 * ks + hi) ^ swz;
            short8 kf = *(const short8*)(Ks + krow * 128 + c * 8);
            S[kvt] = __builtin_amdgcn_mfma_f32_32x32x16_bf16(kf, qf[ks], S[kvt], 0, 0, 0);
          }
          __builtin_amdgcn_s_setprio(0);
          if (kvbase + 31 > qlo) {   // diagonal tile: causal mask
#pragma unroll
            for (int r = 0; r < 16; ++r) {
              int kv = kvbase + (r & 3) + 8 * (r >> 2) + 4 * hi;
              if (kv > qrow) S[kvt][r] = -3.0e38f;
            }
          }
        } else {
#pragma unroll
          for (int r = 0; r < 16; ++r) S[kvt][r] = -3.0e38f;
        }
      }

      // ---- in-register online softmax (one lane^32 exchange per reduce) ----
      float rl = -3.0e38f;
#pragma unroll
      for (int kvt = 0; kvt < 2; ++kvt)
#pragma unroll
        for (int r = 0; r < 16; ++r) rl = fmaxf(rl, S[kvt][r]);
      rl = fmaxf(rl, __shfl_xor(rl, 32, 64));
      float mn = fmaxf(m, rl);
      float fac = exp2f((m - mn) * LOG2E);
      m = mn;
      float sum = 0.0f;
#pragma unroll
      for (int kvt = 0; kvt < 2; ++kvt)
#pragma unroll
        for (int r = 0; r < 16; ++r) {
          float p = exp2f((S[kvt][r] - m) * LOG2E);
          S[kvt][r] = p;
          sum += p;
        }
      sum += __shfl_xor(sum, 32, 64);
      l = l * fac + sum;
#pragma unroll
      for (int dt = 0; dt < 4; ++dt)
#pragma unroll
        for (int r = 0; r < 16; ++r) O[dt][r] *= fac;

      // ---- P -> bf16 B-fragments (corrected exchange) ----
      // S regs [base,base+4) hold kv = 16*sub + (r&3) + 4*hi   ("L")
      //        [base+4,base+8) hold kv = 16*sub + 8 + (r&3) + 4*hi ("H")
      // pf target: slot i <-> kv = 16*sub + 8*hi + i.
      // hi=0 keeps L (kv 0-3), needs partner L (kv 4-7), sends H (kv 8-11).
      // hi=1 keeps H (kv 12-15), needs partner H (kv 8-11), sends L (kv 4-7).
      short8 pf[4];
#pragma unroll
      for (int ks = 0; ks < 4; ++ks) {
        const int kvt = ks >> 1;
        const int base = (ks & 1) * 8;
        unsigned pkL0, pkL1, pkH0, pkH1;
        {
          float a0 = S[kvt][base + 0], a1 = S[kvt][base + 1];
          float a2 = S[kvt][base + 2], a3 = S[kvt][base + 3];
          float b0 = S[kvt][base + 4], b1 = S[kvt][base + 5];
          float b2 = S[kvt][base + 6], b3 = S[kvt][base + 7];
          asm("v_cvt_pk_bf16_f32 %0, %1, %2" : "=v"(pkL0) : "v"(a0), "v"(a1));
          asm("v_cvt_pk_bf16_f32 %0, %1, %2" : "=v"(pkL1) : "v"(a2), "v"(a3));
          asm("v_cvt_pk_bf16_f32 %0, %1, %2" : "=v"(pkH0) : "v"(b0), "v"(b1));
          asm("v_cvt_pk_bf16_f32 %0, %1, %2" : "=v"(pkH1) : "v"(b2), "v"(b3));
        }
        unsigned sx0 = hi ? pkL0 : pkH0;
        unsigned sx1 = hi ? pkL1 : pkH1;
        unsigned rx0 = (unsigned)__shfl_xor((int)sx0, 32, 64);
        unsigned rx1 = (unsigned)__shfl_xor((int)sx1, 32, 64);
        union { unsigned u[4]; short8 s; } uu;
        uu.u[0] = hi ? rx0 : pkL0;   // i0,i1
        uu.u[1] = hi ? rx1 : pkL1;   // i2,i3
        uu.u[2] = hi ? pkH0 : rx0;   // i4,i5
        uu.u[3] = hi ? pkH1 : rx1;   // i6,i7
        pf[ks] = uu.s;
      }

      // ---- O^T += V^T P^T ----
      __builtin_amdgcn_s_setprio(1);
#pragma unroll
      for (int dt = 0; dt < 4; ++dt) {
        const int vrow = dt * 32 + l31;
#pragma unroll
        for (int ks = 0; ks < 4; ++ks) {
          int c = (2 * ks + hi) ^ swz;
          short8 vf = *(const short8*)(Vs + vrow * 64 + c * 8);
          O[dt] = __builtin_amdgcn_mfma_f32_32x32x16_bf16(vf, pf[ks], O[dt], 0, 0, 0);
        }
      }
      __builtin_amdgcn_s_setprio(0);
    }

    __syncthreads();   // all waves done with buf; kt+1 staging landed
    buf ^= 1;
  }
#undef STAGE_TILES

  // ---- epilogue: O^T -> LDS transpose -> coalesced global store ----
  float inv = 1.0f / l;
  bf16_t* ol = smem + w * 4352;   // per-wave 32 x 136 region (272B rows, 16B-aligned)
#pragma unroll
  for (int dt = 0; dt < 4; ++dt)
#pragma unroll
    for (int r = 0; r < 16; ++r) {
      int d = dt * 32 + (r & 3) + 8 * (r >> 2) + 4 * hi;
      *(unsigned short*)&ol[l31 * 136 + d] = f2bf(O[dt][r] * inv);
    }
  __syncthreads();
  const int srow4 = lane >> 4;         // 0..3
  const int scol = (lane & 15) * 8;    // 0..120
#pragma unroll
  for (int rr = 0; rr < 8; ++rr) {
    int row = rr * 4 + srow4;
    short8 v = *(const short8*)(ol + row * 136 + scol);
    *(short8*)(attn + ((size_t)b * T_SEQ + qt * 128 + w * 32 + row) * D_MODEL +
               (size_t)h * HEAD_DIM + scol) = v;
  }
}

// ---------------- launch ----------------
extern "C" void kernel_launch(void* const* d_in, const int* in_sizes, int n_in,
                              void* d_out, int out_size, void* d_ws, size_t ws_size,
                              hipStream_t stream) {
  const float* x    = (const float*)d_in[0];
  const float* cosb = (const float*)d_in[1];
  const float* sinb = (const float*)d_in[2];
  const float* Wqkv = (const float*)d_in[3];
  const float* Wout = (const float*)d_in[4];
  float* out = (float*)d_out;

  char* ws = (char*)d_ws;
  size_t off = 0;
  bf16_t* xb    = (bf16_t*)(ws + off); off += (size_t)4096 * 2048 * 2;
  bf16_t* wqkvb = (bf16_t*)(ws + off); off += (size_t)6144 * 2048 * 2;
  bf16_t* woutb = (bf16_t*)(ws + off); off += (size_t)2048 * 2048 * 2;
  bf16_t* qkvb  = (bf16_t*)(ws + off); off += (size_t)4096 * 6144 * 2;
  bf16_t* qb    = (bf16_t*)(ws + off); off += (size_t)32 * 2048 * 128 * 2;
  bf16_t* kb    = (bf16_t*)(ws + off); off += (size_t)32 * 2048 * 128 * 2;
  bf16_t* vTb   = (bf16_t*)(ws + off); off += (size_t)32 * 2048 * 128 * 2;
  bf16_t* attnb = xb;  // xb dead after QKV GEMM

  cvt_kernel<<<8192, 256, 0, stream>>>(x, (unsigned short*)xb, 4096 * 2048 / 4);
  cvt_kernel<<<12288, 256, 0, stream>>>(Wqkv, (unsigned short*)wqkvb, 6144 * 2048 / 4);
  cvt_kernel<<<4096, 256, 0, stream>>>(Wout, (unsigned short*)woutb, 2048 * 2048 / 4);

  // QKV: M=4096, N=6144 -> 32x24 = 768 blocks
  gemm_tp_kernel<0><<<768, 512, 0, stream>>>(xb, wqkvb, nullptr, (unsigned short*)qkvb,
                                             4096, 6144, 2048, 24);

  rope_kernel<<<1024, 256, 0, stream>>>(qkvb, cosb, sinb, qb, kb, vTb);

  // 512 blocks: 32 bh x 16 q-tiles of 128 rows; 2 blocks/CU, paired workloads
  attn_kernel<<<512, 256, 0, stream>>>(qb, kb, vTb, (unsigned short*)attnb);

  // out-proj: M=4096, N=2048 -> 32x8 = 256 blocks
  gemm_tp_kernel<1><<<256, 512, 0, stream>>>(attnb, woutb, out, nullptr,
                                             4096, 2048, 2048, 8);
}